// Round 5
// baseline (294.790 us; speedup 1.0000x reference)
//
#include <hip/hip_runtime.h>
#include <stdint.h>

// B=2, C=4, D=64, H=256, W=256
// out = sum_{interior, keep} ||omega_p - omega_t||_2 / sum(keep)
// keep = all 27 masks in 3x3x3 neighborhood == 1; omega = neighbor diffs of
// (pred - targ) ch1..3 (SCALES=10 cancels 2*DELTA=10).
//
// R6 post-mortem: __launch_bounds__(256,4) did NOT raise VGPR (56) -- launch
// bounds only cap; the scheduler still sinks every load next to its consumer
// (~3-4 in flight, serialized latency rounds). R1/R2/R4 all pin at ~96us with
// very different load counts => per-wave latency-round serialization.
//
// R7: take the schedule away from the compiler. The 17 fresh loads per step
// are asm volatile global_load_dwordx4 (program-order pinned, named "=v"
// pads the allocator must keep live), then ONE s_waitcnt vmcnt(0) +
// sched_barrier(0) (rule #18), then consume. 32-bit voffset + SGPR tensor
// base (tensors 128MB < 4GB), offset:+-1024 immediates for h+-1 rows.
// 5 serialized rounds/step -> 1. 17KB in flight per wave >> 9KB/CU needed.
// Engagement keys: VGPR ~110-160, WRITE_SIZE stays ~KB (no scratch).

typedef float f4 __attribute__((ext_vector_type(4)));

#define SDB 262144u     // bytes per d-plane   (65536 floats)
#define SCB 16777216u   // bytes per channel   (4194304 floats)

// dst <- *(base + voff + imm), pinned in program order, pad stays live
#define GLOAD(dst, base, voff, imm)                                   \
    asm volatile("global_load_dwordx4 %0, %1, %2 offset:" #imm        \
                 : "=v"(dst) : "v"(voff), "s"(base))

#define VMWAIT()                                                      \
    do { asm volatile("s_waitcnt vmcnt(0)" ::: "memory");             \
         __builtin_amdgcn_sched_barrier(0); } while (0)

__device__ __forceinline__ f4 min4(f4 a, f4 b) {
    f4 r;
    r.x = fminf(a.x, b.x); r.y = fminf(a.y, b.y);
    r.z = fminf(a.z, b.z); r.w = fminf(a.w, b.w);
    return r;
}

__global__ __launch_bounds__(256, 2) void vort_asm(
    const float* __restrict__ preds, const float* __restrict__ targs,
    const float* __restrict__ masks, double* __restrict__ acc, int slot_mask)
{
    const int lane = threadIdx.x & 63;
    const int wv   = threadIdx.x >> 6;
    int blk = blockIdx.x;
    const int tile = blk & 63; blk >>= 6;       // 64 h-tiles of 4 rows
    const int c    = blk & 15; blk >>= 4;       // 16 d-chunks
    const int b    = blk;                       // 0..1
    const int d0   = 1 + 4 * c;                 // chunk covers d0..d0+nstep-1
    const int nstep = (c < 15) ? 4 : 2;         // d interior 1..62
    const int h = 1 + tile * 4 + wv;            // one row per wave
    const int w0 = lane << 2;                   // 4 w per lane, full 256 row

    float norm = 0.0f, cnt = 0.0f;

    if (h <= 254) {   // wave-uniform guard
        const uint32_t rowb = (uint32_t)(h * 256 + w0) * 4u;
        uint32_t a_m = (uint32_t)(b * 64 + d0) * SDB + rowb;           // mask(b,0,d0,h)
        uint32_t a_u = (uint32_t)((b * 4 + 1) * 64 + d0) * SDB + rowb; // u(d0,h)
        uint32_t a_v = a_u + SCB;                                      // v(d0,h)
        uint32_t a_w = a_v + SCB;                                      // w(d0,h)

        // ---- prologue: 14 loads, ONE latency round ----
        f4 Pu0, Pu1, Pv0, Pv1, Tu0, Tu1, Tv0, Tv1;
        f4 Ma0, Mb0, Mc0, Ma1, Mb1, Mc1;
        GLOAD(Pu0, preds, a_u - SDB, 0);
        GLOAD(Pu1, preds, a_u,       0);
        GLOAD(Pv0, preds, a_v - SDB, 0);
        GLOAD(Pv1, preds, a_v,       0);
        GLOAD(Tu0, targs, a_u - SDB, 0);
        GLOAD(Tu1, targs, a_u,       0);
        GLOAD(Tv0, targs, a_v - SDB, 0);
        GLOAD(Tv1, targs, a_v,       0);
        GLOAD(Ma0, masks, a_m - SDB, -1024);
        GLOAD(Mb0, masks, a_m - SDB, 0);
        GLOAD(Mc0, masks, a_m - SDB, 1024);
        GLOAD(Ma1, masks, a_m,       -1024);
        GLOAD(Mb1, masks, a_m,       0);
        GLOAD(Mc1, masks, a_m,       1024);
        VMWAIT();

        // rolling state: u/v center-row diffs at d-1,d ; mask plane h-mins
        f4 cu0 = Pu0 - Tu0, cu1 = Pu1 - Tu1;
        f4 cv0 = Pv0 - Tv0, cv1 = Pv1 - Tv1;
        f4 m0  = min4(Ma0, min4(Mb0, Mc0));
        f4 m1  = min4(Ma1, min4(Mb1, Mc1));

        for (int s = 0; s < nstep; ++s) {
            // ---- 17 fresh loads, pinned, ONE latency round ----
            f4 PuN, Puhm, Puhp, PvN, Pwm, Pwc, Pwp;
            f4 TuN, Tuhm, Tuhp, TvN, Twm, Twc, Twp;
            f4 MaN, MbN, McN;
            GLOAD(PuN,  preds, a_u + SDB, 0);
            GLOAD(Puhm, preds, a_u,       -1024);
            GLOAD(Puhp, preds, a_u,       1024);
            GLOAD(PvN,  preds, a_v + SDB, 0);
            GLOAD(Pwm,  preds, a_w,       -1024);
            GLOAD(Pwc,  preds, a_w,       0);
            GLOAD(Pwp,  preds, a_w,       1024);
            GLOAD(TuN,  targs, a_u + SDB, 0);
            GLOAD(Tuhm, targs, a_u,       -1024);
            GLOAD(Tuhp, targs, a_u,       1024);
            GLOAD(TvN,  targs, a_v + SDB, 0);
            GLOAD(Twm,  targs, a_w,       -1024);
            GLOAD(Twc,  targs, a_w,       0);
            GLOAD(Twp,  targs, a_w,       1024);
            GLOAD(MaN,  masks, a_m + SDB, -1024);
            GLOAD(MbN,  masks, a_m + SDB, 0);
            GLOAD(McN,  masks, a_m + SDB, 1024);
            VMWAIT();

            // ---- consume ----
            f4 cu2 = PuN - TuN;                     // u(d+1,h)
            f4 uhm = Puhm - Tuhm;                   // u(d,h-1)
            f4 uhp = Puhp - Tuhp;                   // u(d,h+1)
            f4 cv2 = PvN - TvN;                     // v(d+1,h)
            f4 wm  = Pwm - Twm;                     // w(d,h-1)
            f4 wc4 = Pwc - Twc;                     // w(d,h)
            f4 wp  = Pwp - Twp;                     // w(d,h+1)
            f4 m2  = min4(MaN, min4(MbN, McN));     // mask plane d+1 h-min
            f4 keep4 = min4(m0, min4(m1, m2));      // 3x3 d,h mask min

            const float vLs = __shfl_up(cv1.w, 1, 64);
            const float vRs = __shfl_down(cv1.x, 1, 64);
            const float wLs = __shfl_up(wc4.w, 1, 64);
            const float wRs = __shfl_down(wc4.x, 1, 64);
            const float kLs = __shfl_up(keep4.w, 1, 64);
            const float kRs = __shfl_down(keep4.x, 1, 64);

            const float vv[6] = { vLs, cv1.x, cv1.y, cv1.z, cv1.w, vRs };
            const float ww[6] = { wLs, wc4.x, wc4.y, wc4.z, wc4.w, wRs };
            const float kk[6] = { kLs, keep4.x, keep4.y, keep4.z, keep4.w, kRs };

            #pragma unroll
            for (int j = 0; j < 4; ++j) {
                const int wcI = w0 + j;
                const float keep = fminf(fminf(kk[j], kk[j + 1]), kk[j + 2]);
                const bool valid = (wcI >= 1) && (wcI <= 254) && (keep > 0.5f);
                const float wx = (wp[j] - wm[j]) - (cv2[j] - cv0[j]);
                const float wy = (cu2[j] - cu0[j]) - (ww[j + 2] - ww[j]);
                const float wz = (vv[j + 2] - vv[j]) - (uhp[j] - uhm[j]);
                const float n = sqrtf(wx * wx + wy * wy + wz * wz);
                norm += valid ? n : 0.0f;
                cnt  += valid ? 1.0f : 0.0f;
            }

            // rotate rolling windows; advance plane
            cu0 = cu1; cu1 = cu2;
            cv0 = cv1; cv1 = cv2;
            m0  = m1;  m1  = m2;
            a_u += SDB; a_v += SDB; a_w += SDB; a_m += SDB;
        }
    }

    // ---- reduction: wave shuffle -> LDS across 4 waves -> spread atomic ----
    #pragma unroll
    for (int off = 32; off > 0; off >>= 1) {
        norm += __shfl_down(norm, off, 64);
        cnt  += __shfl_down(cnt,  off, 64);
    }
    __shared__ float ssum[4], scnt[4];
    if (lane == 0) { ssum[wv] = norm; scnt[wv] = cnt; }
    __syncthreads();
    if (threadIdx.x == 0) {
        const float s = ssum[0] + ssum[1] + ssum[2] + ssum[3];
        const float c2 = scnt[0] + scnt[1] + scnt[2] + scnt[3];
        double* slot = acc + 2 * (blockIdx.x & slot_mask);
        atomicAdd(&slot[0], (double)s);
        atomicAdd(&slot[1], (double)c2);
    }
}

__global__ __launch_bounds__(256) void finalize_kernel(
    const double* __restrict__ acc, float* __restrict__ out, int nslots)
{
    const int lane = threadIdx.x & 63;
    const int wv   = threadIdx.x >> 6;
    double s = 0.0, c = 0.0;
    for (int i = threadIdx.x; i < nslots; i += 256) {
        s += acc[2 * i];
        c += acc[2 * i + 1];
    }
    #pragma unroll
    for (int off = 32; off > 0; off >>= 1) {
        s += __shfl_down(s, off, 64);
        c += __shfl_down(c, off, 64);
    }
    __shared__ double ss[4], sc[4];
    if (lane == 0) { ss[wv] = s; sc[wv] = c; }
    __syncthreads();
    if (threadIdx.x == 0) {
        const double S = ss[0] + ss[1] + ss[2] + ss[3];
        const double C = sc[0] + sc[1] + sc[2] + sc[3];
        out[0] = (C != 0.0) ? (float)(S / C) : 0.0f;
    }
}

extern "C" void kernel_launch(void* const* d_in, const int* in_sizes, int n_in,
                              void* d_out, int out_size, void* d_ws, size_t ws_size,
                              hipStream_t stream)
{
    const float* preds = (const float*)d_in[0];
    const float* targs = (const float*)d_in[1];
    const float* masks = (const float*)d_in[2];
    float* out = (float*)d_out;
    double* acc = (double*)d_ws;

    // 256 slot pairs (4 KB); fall back to fewer if workspace is tiny.
    int nslots = 256;
    while ((size_t)nslots * 2 * sizeof(double) > ws_size && nslots > 1)
        nslots >>= 1;

    hipMemsetAsync(d_ws, 0, (size_t)nslots * 2 * sizeof(double), stream);

    const int nblocks = 2 * 16 * 64;   // (b, d-chunk, h-tile)
    vort_asm<<<nblocks, 256, 0, stream>>>(preds, targs, masks, acc,
                                          nslots - 1);
    finalize_kernel<<<1, 256, 0, stream>>>(acc, out, nslots);
}

// Round 6
// 286.406 us; speedup vs baseline: 1.0293x; 1.0293x over previous
//
#include <hip/hip_runtime.h>
#include <stdint.h>

// B=2, C=4, D=64, H=256, W=256
// out = sum_{interior, keep} ||omega_p - omega_t||_2 / sum(keep)
// keep = all 27 masks in 3x3x3 neighborhood == 1; omega = neighbor diffs of
// (pred - targ) ch1..3 (SCALES=10 cancels 2*DELTA=10).
//
// R7 post-mortem: asm-pinned VGPR loads STILL ran at VGPR=56 (17 live f4
// pads need >=68) -> the allocator/scheduler defeated batching a third time;
// dur pinned at ~96-99us across R1/R2/R4/R5. VGPR landing pads are the
// allocator's resource; it always wins.
//
// R8: global_load_lds (LDS-DMA, the CDNA cp.async). NO destination VGPRs ->
// nothing to serialize. Per step each wave fires 14 DMAs (7 pred + 7 targ,
// 1KB each) back-to-back into its private LDS region, ONE s_waitcnt vmcnt(0)
// + sched_barrier(0) (rule #18), then ds_read_b128 + compute. Masks (3/step)
// stay as plain VGPR loads. 8 waves/CU x 14KB in flight >> 9KB/CU needed.
// Engagement proof: LDS_Block_Size 512 -> ~57KB. Target 40-60us.

typedef float f4 __attribute__((ext_vector_type(4)));

#define SDB 262144u     // bytes per d-plane   (65536 floats)
#define SCB 16777216u   // bytes per channel   (4194304 floats)

// async DMA: 16B per lane, global (per-lane addr) -> LDS (wave-uniform base
// + lane*16). Tracked by vmcnt. No dest VGPRs.
__device__ __forceinline__ void gl_lds16(const void* g, void* l) {
    __builtin_amdgcn_global_load_lds(
        (const __attribute__((address_space(1))) void*)g,
        (__attribute__((address_space(3))) void*)l, 16, 0, 0);
}

#define VMWAIT()                                                      \
    do { asm volatile("s_waitcnt vmcnt(0)" ::: "memory");             \
         __builtin_amdgcn_sched_barrier(0); } while (0)
// drain ds_reads before DMA overwrites the slots next iteration
#define LGKMWAIT()                                                    \
    do { asm volatile("s_waitcnt lgkmcnt(0)" ::: "memory"); } while (0)

__device__ __forceinline__ f4 min4(f4 a, f4 b) {
    f4 r;
    r.x = fminf(a.x, b.x); r.y = fminf(a.y, b.y);
    r.z = fminf(a.z, b.z); r.w = fminf(a.w, b.w);
    return r;
}

__global__ __launch_bounds__(256, 2) void vort_dma(
    const float* __restrict__ preds, const float* __restrict__ targs,
    const float* __restrict__ masks, double* __restrict__ acc, int slot_mask)
{
    // 14 slots x 1KB per wave, 4 waves = 56KB (plus reduction arrays)
    __shared__ float sbuf[4][14 * 256];

    const int lane = threadIdx.x & 63;
    const int wv   = threadIdx.x >> 6;
    int blk = blockIdx.x;
    const int tile = blk & 63; blk >>= 6;       // 64 h-tiles of 4 rows
    const int c    = blk & 15; blk >>= 4;       // 16 d-chunks
    const int b    = blk;                       // 0..1
    const int d0   = 1 + 4 * c;                 // chunk covers d0..d0+nstep-1
    const int nstep = (c < 15) ? 4 : 2;         // d interior 1..62
    const int h = 1 + tile * 4 + wv;            // one row per wave
    const int w0 = lane << 2;                   // 4 w per lane, full 256 row

    float norm = 0.0f, cnt = 0.0f;

    if (h <= 254) {   // wave-uniform guard
        const uint32_t rowb = (uint32_t)(h * 256 + w0) * 4u;
        uint32_t a_m = (uint32_t)(b * 64 + d0) * SDB + rowb;           // mask
        uint32_t a_u = (uint32_t)((b * 4 + 1) * 64 + d0) * SDB + rowb; // u
        uint32_t a_v = a_u + SCB;                                      // v
        uint32_t a_w = a_v + SCB;                                      // w
        const char* pc = (const char*)preds;
        const char* tc = (const char*)targs;
        const char* mc = (const char*)masks;
        float* sb = sbuf[wv];
        const int lb = lane << 2;               // float idx of lane's 16B

#define LDSLOT(k) (*(const f4*)(sb + (k) * 256 + lb))

        // ---- prologue: 8 DMAs (u/v planes d0-1,d0) + 6 mask loads ----
        gl_lds16(pc + (a_u - SDB), sb + 0 * 256);
        gl_lds16(pc + a_u,         sb + 1 * 256);
        gl_lds16(pc + (a_v - SDB), sb + 2 * 256);
        gl_lds16(pc + a_v,         sb + 3 * 256);
        gl_lds16(tc + (a_u - SDB), sb + 4 * 256);
        gl_lds16(tc + a_u,         sb + 5 * 256);
        gl_lds16(tc + (a_v - SDB), sb + 6 * 256);
        gl_lds16(tc + a_v,         sb + 7 * 256);
        const f4 Ma0 = *(const f4*)(mc + (a_m - SDB - 1024));
        const f4 Mb0 = *(const f4*)(mc + (a_m - SDB));
        const f4 Mc0 = *(const f4*)(mc + (a_m - SDB + 1024));
        const f4 Ma1 = *(const f4*)(mc + (a_m - 1024));
        const f4 Mb1 = *(const f4*)(mc + a_m);
        const f4 Mc1 = *(const f4*)(mc + (a_m + 1024));
        VMWAIT();

        // rolling state: u/v center-row diffs at d-1,d ; mask plane h-mins
        f4 cu0 = LDSLOT(0) - LDSLOT(4), cu1 = LDSLOT(1) - LDSLOT(5);
        f4 cv0 = LDSLOT(2) - LDSLOT(6), cv1 = LDSLOT(3) - LDSLOT(7);
        f4 m0  = min4(Ma0, min4(Mb0, Mc0));
        f4 m1  = min4(Ma1, min4(Mb1, Mc1));

        for (int s = 0; s < nstep; ++s) {
            // ---- stage 14 fresh rows via DMA (no dest VGPRs) ----
            LGKMWAIT();   // prior ds_reads done before slots are overwritten
            gl_lds16(pc + (a_u + SDB),  sb + 0 * 256);   // u d+1
            gl_lds16(pc + (a_u - 1024), sb + 1 * 256);   // u h-1
            gl_lds16(pc + (a_u + 1024), sb + 2 * 256);   // u h+1
            gl_lds16(pc + (a_v + SDB),  sb + 3 * 256);   // v d+1
            gl_lds16(pc + (a_w - 1024), sb + 4 * 256);   // w h-1
            gl_lds16(pc + a_w,          sb + 5 * 256);   // w c
            gl_lds16(pc + (a_w + 1024), sb + 6 * 256);   // w h+1
            gl_lds16(tc + (a_u + SDB),  sb + 7 * 256);
            gl_lds16(tc + (a_u - 1024), sb + 8 * 256);
            gl_lds16(tc + (a_u + 1024), sb + 9 * 256);
            gl_lds16(tc + (a_v + SDB),  sb + 10 * 256);
            gl_lds16(tc + (a_w - 1024), sb + 11 * 256);
            gl_lds16(tc + a_w,          sb + 12 * 256);
            gl_lds16(tc + (a_w + 1024), sb + 13 * 256);
            const f4 MaN = *(const f4*)(mc + (a_m + SDB - 1024));
            const f4 MbN = *(const f4*)(mc + (a_m + SDB));
            const f4 McN = *(const f4*)(mc + (a_m + SDB + 1024));
            VMWAIT();

            // ---- consume from LDS ----
            f4 cu2 = LDSLOT(0) - LDSLOT(7);         // u(d+1,h)
            f4 uhm = LDSLOT(1) - LDSLOT(8);         // u(d,h-1)
            f4 uhp = LDSLOT(2) - LDSLOT(9);         // u(d,h+1)
            f4 cv2 = LDSLOT(3) - LDSLOT(10);        // v(d+1,h)
            f4 wm  = LDSLOT(4) - LDSLOT(11);        // w(d,h-1)
            f4 wc4 = LDSLOT(5) - LDSLOT(12);        // w(d,h)
            f4 wp  = LDSLOT(6) - LDSLOT(13);        // w(d,h+1)
            f4 m2  = min4(MaN, min4(MbN, McN));     // mask plane d+1 h-min
            f4 keep4 = min4(m0, min4(m1, m2));      // 3x3 d,h mask min

            const float vLs = __shfl_up(cv1.w, 1, 64);
            const float vRs = __shfl_down(cv1.x, 1, 64);
            const float wLs = __shfl_up(wc4.w, 1, 64);
            const float wRs = __shfl_down(wc4.x, 1, 64);
            const float kLs = __shfl_up(keep4.w, 1, 64);
            const float kRs = __shfl_down(keep4.x, 1, 64);

            const float vv[6] = { vLs, cv1.x, cv1.y, cv1.z, cv1.w, vRs };
            const float ww[6] = { wLs, wc4.x, wc4.y, wc4.z, wc4.w, wRs };
            const float kk[6] = { kLs, keep4.x, keep4.y, keep4.z, keep4.w, kRs };

            #pragma unroll
            for (int j = 0; j < 4; ++j) {
                const int wcI = w0 + j;
                const float keep = fminf(fminf(kk[j], kk[j + 1]), kk[j + 2]);
                const bool valid = (wcI >= 1) && (wcI <= 254) && (keep > 0.5f);
                const float wx = (wp[j] - wm[j]) - (cv2[j] - cv0[j]);
                const float wy = (cu2[j] - cu0[j]) - (ww[j + 2] - ww[j]);
                const float wz = (vv[j + 2] - vv[j]) - (uhp[j] - uhm[j]);
                const float n = sqrtf(wx * wx + wy * wy + wz * wz);
                norm += valid ? n : 0.0f;
                cnt  += valid ? 1.0f : 0.0f;
            }

            // rotate rolling windows; advance plane
            cu0 = cu1; cu1 = cu2;
            cv0 = cv1; cv1 = cv2;
            m0  = m1;  m1  = m2;
            a_u += SDB; a_v += SDB; a_w += SDB; a_m += SDB;
        }
#undef LDSLOT
    }

    // ---- reduction: wave shuffle -> LDS across 4 waves -> spread atomic ----
    #pragma unroll
    for (int off = 32; off > 0; off >>= 1) {
        norm += __shfl_down(norm, off, 64);
        cnt  += __shfl_down(cnt,  off, 64);
    }
    __shared__ float ssum[4], scnt[4];
    if (lane == 0) { ssum[wv] = norm; scnt[wv] = cnt; }
    __syncthreads();
    if (threadIdx.x == 0) {
        const float s = ssum[0] + ssum[1] + ssum[2] + ssum[3];
        const float c2 = scnt[0] + scnt[1] + scnt[2] + scnt[3];
        double* slot = acc + 2 * (blockIdx.x & slot_mask);
        atomicAdd(&slot[0], (double)s);
        atomicAdd(&slot[1], (double)c2);
    }
}

__global__ __launch_bounds__(256) void finalize_kernel(
    const double* __restrict__ acc, float* __restrict__ out, int nslots)
{
    const int lane = threadIdx.x & 63;
    const int wv   = threadIdx.x >> 6;
    double s = 0.0, c = 0.0;
    for (int i = threadIdx.x; i < nslots; i += 256) {
        s += acc[2 * i];
        c += acc[2 * i + 1];
    }
    #pragma unroll
    for (int off = 32; off > 0; off >>= 1) {
        s += __shfl_down(s, off, 64);
        c += __shfl_down(c, off, 64);
    }
    __shared__ double ss[4], sc[4];
    if (lane == 0) { ss[wv] = s; sc[wv] = c; }
    __syncthreads();
    if (threadIdx.x == 0) {
        const double S = ss[0] + ss[1] + ss[2] + ss[3];
        const double C = sc[0] + sc[1] + sc[2] + sc[3];
        out[0] = (C != 0.0) ? (float)(S / C) : 0.0f;
    }
}

extern "C" void kernel_launch(void* const* d_in, const int* in_sizes, int n_in,
                              void* d_out, int out_size, void* d_ws, size_t ws_size,
                              hipStream_t stream)
{
    const float* preds = (const float*)d_in[0];
    const float* targs = (const float*)d_in[1];
    const float* masks = (const float*)d_in[2];
    float* out = (float*)d_out;
    double* acc = (double*)d_ws;

    // 256 slot pairs (4 KB); fall back to fewer if workspace is tiny.
    int nslots = 256;
    while ((size_t)nslots * 2 * sizeof(double) > ws_size && nslots > 1)
        nslots >>= 1;

    hipMemsetAsync(d_ws, 0, (size_t)nslots * 2 * sizeof(double), stream);

    const int nblocks = 2 * 16 * 64;   // (b, d-chunk, h-tile)
    vort_dma<<<nblocks, 256, 0, stream>>>(preds, targs, masks, acc,
                                          nslots - 1);
    finalize_kernel<<<1, 256, 0, stream>>>(acc, out, nslots);
}